// Round 22
// baseline (133.529 us; speedup 1.0000x reference)
//
#include <hip/hip_runtime.h>
#include <math.h>

#define BTOT   32768
#define LAT    128
#define H      17
#define G4     68      // 4*H
#define TSTEPS 50
#define NPR    102     // projection rows: 68 (W_ih) + 17 (W_h0) + 17 (W_c0)
#define WPAD   40      // Wbuf row stride (k-quarter staging, R14-proven)
#define XPAD   132

#define NW     4              // waves per block (small blocks -> decorrelated)
#define RPB    12             // 3 rows per wave, 51/64 lanes active
#define TPB    256

// x_tile stride 132: rows r,r+8 alias -> 2-bit XOR key (R13/R14-proven).
#define XSWZ(r, c4)   ((c4) ^ ((((r) >> 3) & 3) << 2))
// Wbuf stride 40: rows r,r+4 alias -> key on bits 2-3 (R14-proven).
#define WSWZ(row, c4) ((c4) ^ ((((row) >> 2) & 3) << 2))

// f32-only gates (R9: recurrence amplifies per-step error ~1e3x; f16 fails).
__device__ __forceinline__ float fsigmoid(float x) {
    float e = __expf(-x);
    return __builtin_amdgcn_rcpf(1.0f + e);
}
// tanh(x) = 1 - 2*rcp(exp(2x)+1); +inf -> 1, -inf -> -1, no divide.
__device__ __forceinline__ float ftanhf(float x) {
    float e = __expf(2.0f * x);
    float t = __builtin_amdgcn_rcpf(e + 1.0f);
    return fmaf(-2.0f, t, 1.0f);
}

// R21 finding: gfx950 VALU CANNOT source AGPRs (assembler rejected a-reg src0)
// -> AGPR-resident W always pays v_accvgpr_read per use. Constraint stays "v".
#define FMAC(acc, w, h) asm("v_fmac_f32 %0, %1, %2" : "+v"(acc) : "v"(w), "v"(h))

#define FQ(Q, HV) \
    FMAC(ai,Wi[4*Q+0],HV.x); FMAC(af,Wf[4*Q+0],HV.x); FMAC(ag,Wg[4*Q+0],HV.x); FMAC(ao,Wo[4*Q+0],HV.x); \
    FMAC(ai,Wi[4*Q+1],HV.y); FMAC(af,Wf[4*Q+1],HV.y); FMAC(ag,Wg[4*Q+1],HV.y); FMAC(ao,Wo[4*Q+1],HV.y); \
    FMAC(ai,Wi[4*Q+2],HV.z); FMAC(af,Wf[4*Q+2],HV.z); FMAC(ag,Wg[4*Q+2],HV.z); FMAC(ao,Wo[4*Q+2],HV.z); \
    FMAC(ai,Wi[4*Q+3],HV.w); FMAC(af,Wf[4*Q+3],HV.w); FMAC(ag,Wg[4*Q+3],HV.w); FMAC(ao,Wo[4*Q+3],HV.w);

// R22 core change: amdgpu_waves_per_eu(4,4) pins min=MAX occupancy at 4 waves/EU.
// Theory: LLVM banks W to AGPRs to shrink ARCH vgprs chasing higher modeled
// occupancy (launch_bounds arg is only a minimum; AGPRs look free in its model).
// With max pinned to what the 128-reg budget already gives, banking has zero
// payoff -> W(68)+state(~45) stays in arch VGPRs -> the 68 copies/set-step
// (R20: ~38% of the issue-saturated instruction stream) disappear.
__global__ __launch_bounds__(TPB) __attribute__((amdgpu_waves_per_eu(4, 4)))
void lstm_fused(const float* __restrict__ x,
                const float* __restrict__ W_h0, const float* __restrict__ b_h0,
                const float* __restrict__ W_c0, const float* __restrict__ b_c0,
                const float* __restrict__ W_ih, const float* __restrict__ W_hh,
                const float* __restrict__ b_ih, const float* __restrict__ b_hh,
                float* __restrict__ out)
{
    __shared__ __align__(16) float x_tile[RPB][XPAD];   //  6.3 KB
    __shared__ __align__(16) float Wbuf[NPR][WPAD];     // 16.3 KB (one k-quarter)
    __shared__ __align__(16) float Wl[G4 * H];          //  4.6 KB (W_hh f32)
    __shared__ __align__(16) float hbuf[NW][3][20];     //  1.0 KB
    // total 28.2 KB; 4 blocks/CU x 4 waves = 16 waves/CU (R20-proven 45%).

    const int t    = threadIdx.x;
    const int w    = t >> 6;
    const int lane = t & 63;
    const bool active = lane < 3 * H;         // 51
    const int rl = active ? (lane / H) : 0;   // 0..2
    const int j  = active ? (lane % H) : 0;   // 0..16
    const int r0 = w * 3 + rl;                // block-local row 0..11
    const int grow0 = blockIdx.x * RPB;
    int grow = grow0 + r0;
    const bool valid = active && (grow < BTOT);
    if (grow >= BTOT) grow = BTOT - 1;

    // ---- stage x tile (rows clamped) + W_hh; all 256 threads ----
    for (int i = t; i < RPB * 32; i += TPB) {              // 384 float4
        int rr = i >> 5, c4 = (i & 31) * 4;
        int gr = grow0 + rr; if (gr >= BTOT) gr = BTOT - 1;
        *(float4*)&x_tile[rr][XSWZ(rr, c4)] = *(const float4*)(x + (size_t)gr * LAT + c4);
    }
    for (int i = t; i < G4 * H; i += TPB) Wl[i] = W_hh[i];

    // ---- phase 1: projections, four k-quarters of 32 (R14-proven layout) ----
    float acc[6] = {0.f, 0.f, 0.f, 0.f, 0.f, 0.f};         // i,f,g,o, h0, c0
    const int rows6[6] = { j, 17 + j, 34 + j, 51 + j, 68 + j, 85 + j };
    for (int qh = 0; qh < 4; ++qh) {
        __syncthreads();  // qh=0: x_tile/Wl ready; else WAR on Wbuf
        for (int i = t; i < NPR * 8; i += TPB) {           // 8 float4 per quarter-row
            int row = i >> 3, c4 = (i & 7) * 4;
            const float* src = (row < G4) ? (W_ih + row * LAT)
                             : (row < 85) ? (W_h0 + (row - G4) * LAT)
                                          : (W_c0 + (row - 85) * LAT);
            *(float4*)&Wbuf[row][WSWZ(row, c4)] = *(const float4*)(src + qh * 32 + c4);
        }
        __syncthreads();  // quarter ready
        for (int kb = 0; kb < 8; ++kb) {
            const int xc = qh * 32 + kb * 4;
            float4 xv = *(const float4*)&x_tile[r0][XSWZ(r0, xc)];
#pragma unroll
            for (int p = 0; p < 6; ++p) {
                const int row = rows6[p];
                float4 wv = *(const float4*)&Wbuf[row][WSWZ(row, kb * 4)];
                acc[p] = fmaf(xv.x, wv.x, acc[p]);
                acc[p] = fmaf(xv.y, wv.y, acc[p]);
                acc[p] = fmaf(xv.z, wv.z, acc[p]);
                acc[p] = fmaf(xv.w, wv.w, acc[p]);
            }
        }
    }

    const float xgi = acc[0] + b_ih[j]      + b_hh[j];
    const float xgf = acc[1] + b_ih[17 + j] + b_hh[17 + j];
    const float xgg = acc[2] + b_ih[34 + j] + b_hh[34 + j];
    const float xgo = acc[3] + b_ih[51 + j] + b_hh[51 + j];
    float h = acc[4] + b_h0[j];
    float c = acc[5] + b_c0[j];

    // ---- W_hh rows for gates i,f,g,o of element j -> arch VGPRs ----
    float Wi[H], Wf[H], Wg[H], Wo[H];
#pragma unroll
    for (int k = 0; k < H; ++k) {
        Wi[k] = Wl[(0 * H + j) * H + k];
        Wf[k] = Wl[(1 * H + j) * H + k];
        Wg[k] = Wl[(2 * H + j) * H + k];
        Wo[k] = Wl[(3 * H + j) * H + k];
        asm volatile("" : "+v"(Wi[k]), "+v"(Wf[k]), "+v"(Wg[k]), "+v"(Wo[k]));
    }

    // ---- phase 2: single-set recurrence, zero barriers (rows wave-local) ----
    const float* hb = &hbuf[w][rl][0];
    float* orow = out + (size_t)grow * (TSTEPS * H) + j;

    for (int tt = 0; tt < TSTEPS; ++tt) {
        if (active) hbuf[w][rl][j] = h;
        // same-wave write->read on hbuf: compiler inserts lgkmcnt wait

        float4 f0 = *(const float4*)&hb[0];
        float4 f1 = *(const float4*)&hb[4];
        float4 f2 = *(const float4*)&hb[8];
        float4 f3 = *(const float4*)&hb[12];
        float  f4 = hb[16];

        float ai = xgi, af = xgf, ag = xgg, ao = xgo;
        FQ(0, f0) FQ(1, f1) FQ(2, f2) FQ(3, f3)
        FMAC(ai, Wi[16], f4); FMAC(af, Wf[16], f4);
        FMAC(ag, Wg[16], f4); FMAC(ao, Wo[16], f4);

        const float ig = fsigmoid(ai), fg = fsigmoid(af);
        const float gv = ftanhf(ag),  og = fsigmoid(ao);
        c = fmaf(fg, c, ig * gv);
        h = og * ftanhf(c);

        if (valid) orow[tt * H] = h;
    }
}

extern "C" void kernel_launch(void* const* d_in, const int* in_sizes, int n_in,
                              void* d_out, int out_size, void* d_ws, size_t ws_size,
                              hipStream_t stream)
{
    const float* x    = (const float*)d_in[0];
    const float* W_h0 = (const float*)d_in[1];
    const float* b_h0 = (const float*)d_in[2];
    const float* W_c0 = (const float*)d_in[3];
    const float* b_c0 = (const float*)d_in[4];
    const float* W_ih = (const float*)d_in[5];
    const float* W_hh = (const float*)d_in[6];
    const float* b_ih = (const float*)d_in[7];
    const float* b_hh = (const float*)d_in[8];
    float* out = (float*)d_out;

    (void)d_ws; (void)ws_size;  // no workspace used

    const int nblk = (BTOT + RPB - 1) / RPB;   // 2731
    hipLaunchKernelGGL(lstm_fused, dim3(nblk), dim3(TPB), 0, stream,
                       x, W_h0, b_h0, W_c0, b_c0, W_ih, W_hh, b_ih, b_hh, out);
}